// Round 1
// baseline (138.027 us; speedup 1.0000x reference)
//
#include <hip/hip_runtime.h>

// Trilinear grid_sample (align_corners=False, zeros padding) of 256^3 fp32
// volume, scaled by 100.
//
// Round 3: z-bucket sort + XCD-affine gather.
//   Counters showed 134 MB HBM fetch == 4 rows/pt * 64B with ~0% L2 reuse:
//   random points spread over 8 XCDs re-fetch every volume line. Fix:
//   (1) scatter points into 256 z-slice buckets (block-aggregated atomics,
//       fixed capacity 2560 = mean 2048 + 11 sigma, overflow computes direct),
//   (2) gather kernel maps bucket -> XCD via blockIdx%8 so each XCD only
//       touches its own 32-slice slab; two z-halves looped in-kernel keep the
//       concurrent per-XCD footprint at ~17 slices ~= 4.25 MB ~= L2 size.

#define RES 256
#define NB 256            // z buckets (one per slice, nearest-slice key)
#define CAP 2560          // slots/bucket: 5 sub-blocks * 512
#define SLOTS_PER_SUB 512
#define SUBS 5

typedef float vfloat4 __attribute__((ext_vector_type(4)));

// ---- shared interp math (verified, absmax 3.8e-6) ----

__device__ __forceinline__ void setup_c(
    float rx, float ry, float rz,
    int& r00, int& r01, int& r10, int& r11, int& xc0, int& xc1,
    float& wx0, float& wx1, float& wy0, float& wy1, float& wz0, float& wz1)
{
    float gx = rx * 2.0f;
    float gy = ry * 2.0f;
    float gz = rz * 2.0f;

    float ix = ((gx + 1.0f) * (float)RES - 1.0f) * 0.5f;
    float iy = ((gy + 1.0f) * (float)RES - 1.0f) * 0.5f;
    float iz = ((gz + 1.0f) * (float)RES - 1.0f) * 0.5f;

    float x0f = floorf(ix), y0f = floorf(iy), z0f = floorf(iz);
    float tx = ix - x0f, ty = iy - y0f, tz = iz - z0f;

    int x0 = (int)x0f, y0 = (int)y0f, z0 = (int)z0f;
    int x1 = x0 + 1, y1 = y0 + 1, z1 = z0 + 1;

    wx0 = (x0 >= 0 && x0 < RES) ? (1.0f - tx) : 0.0f;
    wx1 = (x1 >= 0 && x1 < RES) ? tx : 0.0f;
    wy0 = (y0 >= 0 && y0 < RES) ? (1.0f - ty) : 0.0f;
    wy1 = (y1 >= 0 && y1 < RES) ? ty : 0.0f;
    wz0 = (z0 >= 0 && z0 < RES) ? (1.0f - tz) : 0.0f;
    wz1 = (z1 >= 0 && z1 < RES) ? tz : 0.0f;

    xc0 = min(max(x0, 0), RES - 1); xc1 = min(max(x1, 0), RES - 1);
    int yc0 = min(max(y0, 0), RES - 1), yc1 = min(max(y1, 0), RES - 1);
    int zc0 = min(max(z0, 0), RES - 1), zc1 = min(max(z1, 0), RES - 1);

    r00 = (zc0 * RES + yc0) * RES;
    r01 = (zc0 * RES + yc1) * RES;
    r10 = (zc1 * RES + yc0) * RES;
    r11 = (zc1 * RES + yc1) * RES;
}

__device__ __forceinline__ void point_setup(
    const float* __restrict__ x, int i,
    int& r00, int& r01, int& r10, int& r11, int& xc0, int& xc1,
    float& wx0, float& wx1, float& wy0, float& wy1, float& wz0, float& wz1)
{
    float rx = __builtin_nontemporal_load(&x[3 * i + 0]);
    float ry = __builtin_nontemporal_load(&x[3 * i + 1]);
    float rz = __builtin_nontemporal_load(&x[3 * i + 2]);
    setup_c(rx, ry, rz, r00, r01, r10, r11, xc0, xc1,
            wx0, wx1, wy0, wy1, wz0, wz1);
}

__device__ __forceinline__ float trilerp(
    const float* __restrict__ vol,
    int r00, int r01, int r10, int r11, int xc0, int xc1,
    float wx0, float wx1, float wy0, float wy1, float wz0, float wz1)
{
    float v000 = vol[r00 + xc0];
    float v001 = vol[r00 + xc1];
    float v010 = vol[r01 + xc0];
    float v011 = vol[r01 + xc1];
    float v100 = vol[r10 + xc0];
    float v101 = vol[r10 + xc1];
    float v110 = vol[r11 + xc0];
    float v111 = vol[r11 + xc1];

    float c00 = v000 * wx0 + v001 * wx1;
    float c01 = v010 * wx0 + v011 * wx1;
    float c10 = v100 * wx0 + v101 * wx1;
    float c11 = v110 * wx0 + v111 * wx1;
    float c0 = c00 * wy0 + c01 * wy1;
    float c1 = c10 * wy0 + c11 * wy1;
    return 100.0f * (c0 * wz0 + c1 * wz1);
}

__device__ __forceinline__ float interp_point(
    const float* __restrict__ vol, float rx, float ry, float rz)
{
    int r00, r01, r10, r11, x0, x1;
    float wx0, wx1, wy0, wy1, wz0, wz1;
    setup_c(rx, ry, rz, r00, r01, r10, r11, x0, x1,
            wx0, wx1, wy0, wy1, wz0, wz1);
    return trilerp(vol, r00, r01, r10, r11, x0, x1,
                   wx0, wx1, wy0, wy1, wz0, wz1);
}

// ---- pass 1: bucket-scatter points by z slice ----
// block = 256 threads, 1024 points/block (4/thread).

__global__ __launch_bounds__(256) void VolumeExplicit_scatter_kernel(
    const float* __restrict__ x,
    const float* __restrict__ vol,
    float* __restrict__ out,
    vfloat4* __restrict__ sorted,
    unsigned* __restrict__ cursor)
{
    __shared__ unsigned lh[NB];
    __shared__ unsigned lbase[NB];
    int t = threadIdx.x;
    int base_i = blockIdx.x * 1024;

    lh[t] = 0;
    __syncthreads();

    float px[4], py[4], pz[4];
    int bk[4];
    unsigned lr[4];
    #pragma unroll
    for (int k = 0; k < 4; ++k) {
        int i = base_i + (k << 8) + t;
        px[k] = __builtin_nontemporal_load(&x[3 * i + 0]);
        py[k] = __builtin_nontemporal_load(&x[3 * i + 1]);
        pz[k] = __builtin_nontemporal_load(&x[3 * i + 2]);
        // nearest-slice key: uniform 1/256 per bucket (incl. edges)
        float iz = ((pz[k] * 2.0f + 1.0f) * (float)RES - 1.0f) * 0.5f;
        int b = (int)(iz + 0.5f);          // iz+0.5 in [0,256]
        b = min(max(b, 0), NB - 1);
        bk[k] = b;
        lr[k] = atomicAdd(&lh[b], 1u);     // local rank within (block,bucket)
    }
    __syncthreads();

    unsigned c = lh[t];
    lbase[t] = c ? atomicAdd(&cursor[t], c) : 0u;   // reserve global range
    __syncthreads();

    #pragma unroll
    for (int k = 0; k < 4; ++k) {
        int i = base_i + (k << 8) + t;
        unsigned pos = lbase[bk[k]] + lr[k];
        if (pos < CAP) {
            vfloat4 v;
            v.x = px[k]; v.y = py[k]; v.z = pz[k];
            v.w = __uint_as_float((unsigned)i);
            sorted[bk[k] * CAP + pos] = v;
        } else {
            // overflow insurance (statistically unreachable): compute direct
            out[i] = interp_point(vol, px[k], py[k], pz[k]);
        }
    }
}

// ---- pass 2: XCD-affine gather + trilerp ----
// grid = 640 blocks. blockIdx%8 == XCD (round-robin dispatch):
//   xcd = B&7, j = (B>>3)&15, sub = B>>7; bucket = xcd*32 + h*16 + j.
// Each XCD only ever touches slices [32*xcd, 32*xcd+33); per half ~17 slices
// ~= 4.25 MB ~= its private L2.

__global__ __launch_bounds__(256) void VolumeExplicit_gather_kernel(
    const vfloat4* __restrict__ sorted,
    const unsigned* __restrict__ cursor,
    const float* __restrict__ vol,
    float* __restrict__ out)
{
    int t = threadIdx.x;
    int B = blockIdx.x;
    int xcd = B & 7;
    int r = B >> 3;        // 0..79
    int j = r & 15;        // slice-within-half
    int sub = r >> 4;      // 0..4

    #pragma unroll 1
    for (int h = 0; h < 2; ++h) {
        int bucket = xcd * 32 + h * 16 + j;
        unsigned count = min(cursor[bucket], (unsigned)CAP);
        if (count == 0) continue;
        int cm1 = (int)count - 1;

        int sA = sub * SLOTS_PER_SUB + t;
        int sB = sA + 256;
        bool vA = sA < (int)count;
        bool vB = sB < (int)count;
        int sAc = min(sA, cm1);
        int sBc = min(sB, cm1);

        vfloat4 pA = __builtin_nontemporal_load(&sorted[bucket * CAP + sAc]);
        vfloat4 pB = __builtin_nontemporal_load(&sorted[bucket * CAP + sBc]);

        // setup both points, then all 16 volume loads in flight together
        int a_r00, a_r01, a_r10, a_r11, a_x0, a_x1;
        float a_wx0, a_wx1, a_wy0, a_wy1, a_wz0, a_wz1;
        setup_c(pA.x, pA.y, pA.z, a_r00, a_r01, a_r10, a_r11, a_x0, a_x1,
                a_wx0, a_wx1, a_wy0, a_wy1, a_wz0, a_wz1);

        int b_r00, b_r01, b_r10, b_r11, b_x0, b_x1;
        float b_wx0, b_wx1, b_wy0, b_wy1, b_wz0, b_wz1;
        setup_c(pB.x, pB.y, pB.z, b_r00, b_r01, b_r10, b_r11, b_x0, b_x1,
                b_wx0, b_wx1, b_wy0, b_wy1, b_wz0, b_wz1);

        float oA = trilerp(vol, a_r00, a_r01, a_r10, a_r11, a_x0, a_x1,
                           a_wx0, a_wx1, a_wy0, a_wy1, a_wz0, a_wz1);
        float oB = trilerp(vol, b_r00, b_r01, b_r10, b_r11, b_x0, b_x1,
                           b_wx0, b_wx1, b_wy0, b_wy1, b_wz0, b_wz1);

        if (vA) out[__float_as_uint(pA.w)] = oA;
        if (vB) out[__float_as_uint(pB.w)] = oB;
    }
}

// ---- fallback: previous direct kernel (any shape / small workspace) ----

__global__ __launch_bounds__(256) void VolumeExplicit_29257317220866_kernel(
    const float* __restrict__ x,
    const float* __restrict__ vol,
    float* __restrict__ out,
    int n)
{
    int tid = blockIdx.x * blockDim.x + threadIdx.x;
    int half = n >> 1;
    if (tid >= half) return;
    int iA = tid;
    int iB = tid + half;

    int a_r00, a_r01, a_r10, a_r11, a_x0, a_x1;
    float a_wx0, a_wx1, a_wy0, a_wy1, a_wz0, a_wz1;
    point_setup(x, iA, a_r00, a_r01, a_r10, a_r11, a_x0, a_x1,
                a_wx0, a_wx1, a_wy0, a_wy1, a_wz0, a_wz1);

    int b_r00, b_r01, b_r10, b_r11, b_x0, b_x1;
    float b_wx0, b_wx1, b_wy0, b_wy1, b_wz0, b_wz1;
    point_setup(x, iB, b_r00, b_r01, b_r10, b_r11, b_x0, b_x1,
                b_wx0, b_wx1, b_wy0, b_wy1, b_wz0, b_wz1);

    float oA = trilerp(vol, a_r00, a_r01, a_r10, a_r11, a_x0, a_x1,
                       a_wx0, a_wx1, a_wy0, a_wy1, a_wz0, a_wz1);
    float oB = trilerp(vol, b_r00, b_r01, b_r10, b_r11, b_x0, b_x1,
                       b_wx0, b_wx1, b_wy0, b_wy1, b_wz0, b_wz1);

    __builtin_nontemporal_store(oA, &out[iA]);
    __builtin_nontemporal_store(oB, &out[iB]);
}

extern "C" void kernel_launch(void* const* d_in, const int* in_sizes, int n_in,
                              void* d_out, int out_size, void* d_ws, size_t ws_size,
                              hipStream_t stream) {
    const float* x   = (const float*)d_in[0];   // [8, 65536, 3] fp32
    const float* vol = (const float*)d_in[1];   // [256,256,256] fp32
    float* out = (float*)d_out;                 // [8, 65536] fp32

    int n = out_size;                            // 524288 points
    size_t need = 4096 + (size_t)NB * CAP * sizeof(vfloat4);  // ~10.5 MB

    if (n == 524288 && d_ws != nullptr && ws_size >= need) {
        unsigned* cursor = (unsigned*)d_ws;
        vfloat4* sorted  = (vfloat4*)((char*)d_ws + 4096);

        hipMemsetAsync(cursor, 0, NB * sizeof(unsigned), stream);
        VolumeExplicit_scatter_kernel<<<n / 1024, 256, 0, stream>>>(
            x, vol, out, sorted, cursor);
        VolumeExplicit_gather_kernel<<<8 * 16 * SUBS, 256, 0, stream>>>(
            sorted, cursor, vol, out);
    } else {
        int half = n >> 1;
        int block = 256;
        int grid = (half + block - 1) / block;
        VolumeExplicit_29257317220866_kernel<<<grid, block, 0, stream>>>(x, vol, out, n);
    }
}

// Round 2
// 133.159 us; speedup vs baseline: 1.0366x; 1.0366x over previous
//
#include <hip/hip_runtime.h>

// Trilinear grid_sample (align_corners=False, zeros padding) of 256^3 fp32
// volume, scaled by 100.
//
// Round 4: z-bucket sort + XCD-affine gather, rebalanced.
//   Round 3 result: FETCH halved (129->55 MB, slab affinity works) but gather
//   time flat at 41 us with Occupancy 18% -- latency-bound and wave-starved
//   (640 blocks, 1/5 of them empty). Fix: 256-slot windows, 10 windows per
//   bucket -> 1280 blocks (5 blocks/CU, ~20 waves/CU), 1 pt/thread/phase.
//   Two-phase h-loop kept: concurrent per-XCD footprint ~16 slices ~4.2 MB
//   ~= private L2. out stores nontemporal (partial-sector writes bypass L2,
//   keep volume lines resident).

#define RES 256
#define NB 256            // z buckets (one per slice, nearest-slice key)
#define CAP 2560          // slots/bucket: 10 windows * 256
#define WIN 256           // slots per window (= block size, 1 pt/thread/phase)
#define WINDOWS 10

typedef float vfloat4 __attribute__((ext_vector_type(4)));

// ---- shared interp math (verified, absmax 3.8e-6) ----

__device__ __forceinline__ void setup_c(
    float rx, float ry, float rz,
    int& r00, int& r01, int& r10, int& r11, int& xc0, int& xc1,
    float& wx0, float& wx1, float& wy0, float& wy1, float& wz0, float& wz1)
{
    float gx = rx * 2.0f;
    float gy = ry * 2.0f;
    float gz = rz * 2.0f;

    float ix = ((gx + 1.0f) * (float)RES - 1.0f) * 0.5f;
    float iy = ((gy + 1.0f) * (float)RES - 1.0f) * 0.5f;
    float iz = ((gz + 1.0f) * (float)RES - 1.0f) * 0.5f;

    float x0f = floorf(ix), y0f = floorf(iy), z0f = floorf(iz);
    float tx = ix - x0f, ty = iy - y0f, tz = iz - z0f;

    int x0 = (int)x0f, y0 = (int)y0f, z0 = (int)z0f;
    int x1 = x0 + 1, y1 = y0 + 1, z1 = z0 + 1;

    wx0 = (x0 >= 0 && x0 < RES) ? (1.0f - tx) : 0.0f;
    wx1 = (x1 >= 0 && x1 < RES) ? tx : 0.0f;
    wy0 = (y0 >= 0 && y0 < RES) ? (1.0f - ty) : 0.0f;
    wy1 = (y1 >= 0 && y1 < RES) ? ty : 0.0f;
    wz0 = (z0 >= 0 && z0 < RES) ? (1.0f - tz) : 0.0f;
    wz1 = (z1 >= 0 && z1 < RES) ? tz : 0.0f;

    xc0 = min(max(x0, 0), RES - 1); xc1 = min(max(x1, 0), RES - 1);
    int yc0 = min(max(y0, 0), RES - 1), yc1 = min(max(y1, 0), RES - 1);
    int zc0 = min(max(z0, 0), RES - 1), zc1 = min(max(z1, 0), RES - 1);

    r00 = (zc0 * RES + yc0) * RES;
    r01 = (zc0 * RES + yc1) * RES;
    r10 = (zc1 * RES + yc0) * RES;
    r11 = (zc1 * RES + yc1) * RES;
}

__device__ __forceinline__ void point_setup(
    const float* __restrict__ x, int i,
    int& r00, int& r01, int& r10, int& r11, int& xc0, int& xc1,
    float& wx0, float& wx1, float& wy0, float& wy1, float& wz0, float& wz1)
{
    float rx = __builtin_nontemporal_load(&x[3 * i + 0]);
    float ry = __builtin_nontemporal_load(&x[3 * i + 1]);
    float rz = __builtin_nontemporal_load(&x[3 * i + 2]);
    setup_c(rx, ry, rz, r00, r01, r10, r11, xc0, xc1,
            wx0, wx1, wy0, wy1, wz0, wz1);
}

__device__ __forceinline__ float trilerp(
    const float* __restrict__ vol,
    int r00, int r01, int r10, int r11, int xc0, int xc1,
    float wx0, float wx1, float wy0, float wy1, float wz0, float wz1)
{
    float v000 = vol[r00 + xc0];
    float v001 = vol[r00 + xc1];
    float v010 = vol[r01 + xc0];
    float v011 = vol[r01 + xc1];
    float v100 = vol[r10 + xc0];
    float v101 = vol[r10 + xc1];
    float v110 = vol[r11 + xc0];
    float v111 = vol[r11 + xc1];

    float c00 = v000 * wx0 + v001 * wx1;
    float c01 = v010 * wx0 + v011 * wx1;
    float c10 = v100 * wx0 + v101 * wx1;
    float c11 = v110 * wx0 + v111 * wx1;
    float c0 = c00 * wy0 + c01 * wy1;
    float c1 = c10 * wy0 + c11 * wy1;
    return 100.0f * (c0 * wz0 + c1 * wz1);
}

__device__ __forceinline__ float interp_point(
    const float* __restrict__ vol, float rx, float ry, float rz)
{
    int r00, r01, r10, r11, x0, x1;
    float wx0, wx1, wy0, wy1, wz0, wz1;
    setup_c(rx, ry, rz, r00, r01, r10, r11, x0, x1,
            wx0, wx1, wy0, wy1, wz0, wz1);
    return trilerp(vol, r00, r01, r10, r11, x0, x1,
                   wx0, wx1, wy0, wy1, wz0, wz1);
}

// ---- pass 1: bucket-scatter points by z slice ----
// block = 256 threads, 1024 points/block (4/thread). ~7 us measured.

__global__ __launch_bounds__(256) void VolumeExplicit_scatter_kernel(
    const float* __restrict__ x,
    const float* __restrict__ vol,
    float* __restrict__ out,
    vfloat4* __restrict__ sorted,
    unsigned* __restrict__ cursor)
{
    __shared__ unsigned lh[NB];
    __shared__ unsigned lbase[NB];
    int t = threadIdx.x;
    int base_i = blockIdx.x * 1024;

    lh[t] = 0;
    __syncthreads();

    float px[4], py[4], pz[4];
    int bk[4];
    unsigned lr[4];
    #pragma unroll
    for (int k = 0; k < 4; ++k) {
        int i = base_i + (k << 8) + t;
        px[k] = __builtin_nontemporal_load(&x[3 * i + 0]);
        py[k] = __builtin_nontemporal_load(&x[3 * i + 1]);
        pz[k] = __builtin_nontemporal_load(&x[3 * i + 2]);
        // nearest-slice key: uniform 1/256 per bucket (incl. edges)
        float iz = ((pz[k] * 2.0f + 1.0f) * (float)RES - 1.0f) * 0.5f;
        int b = (int)(iz + 0.5f);          // iz+0.5 in [0,256]
        b = min(max(b, 0), NB - 1);
        bk[k] = b;
        lr[k] = atomicAdd(&lh[b], 1u);     // local rank within (block,bucket)
    }
    __syncthreads();

    unsigned c = lh[t];
    lbase[t] = c ? atomicAdd(&cursor[t], c) : 0u;   // reserve global range
    __syncthreads();

    #pragma unroll
    for (int k = 0; k < 4; ++k) {
        int i = base_i + (k << 8) + t;
        unsigned pos = lbase[bk[k]] + lr[k];
        if (pos < CAP) {
            vfloat4 v;
            v.x = px[k]; v.y = py[k]; v.z = pz[k];
            v.w = __uint_as_float((unsigned)i);
            sorted[bk[k] * CAP + pos] = v;
        } else {
            // overflow insurance (statistically unreachable): compute direct
            out[i] = interp_point(vol, px[k], py[k], pz[k]);
        }
    }
}

// ---- pass 2: XCD-affine gather + trilerp ----
// grid = 1280 blocks. blockIdx%8 == XCD (round-robin dispatch):
//   xcd = B&7, j = (B>>3)&15 (slice-in-half), w = B>>7 (window 0..9).
//   bucket = xcd*32 + h*16 + j; slot = w*256 + tid; 1 pt/thread/phase.
// Per XCD concurrent footprint ~16 slices ~4.2 MB ~= private L2.
// 5 blocks/CU (~20 waves/CU) fixes round-3's 18% occupancy starvation.

__global__ __launch_bounds__(256) void VolumeExplicit_gather_kernel(
    const vfloat4* __restrict__ sorted,
    const unsigned* __restrict__ cursor,
    const float* __restrict__ vol,
    float* __restrict__ out)
{
    int t = threadIdx.x;
    int B = blockIdx.x;
    int xcd = B & 7;
    int r = B >> 3;        // 0..159
    int j = r & 15;        // slice-within-half
    int w = r >> 4;        // window 0..9

    #pragma unroll 1
    for (int h = 0; h < 2; ++h) {
        int bucket = xcd * 32 + h * 16 + j;
        unsigned count = min(cursor[bucket], (unsigned)CAP);
        int s = w * WIN + t;
        if ((unsigned)s >= count) continue;

        vfloat4 p = __builtin_nontemporal_load(&sorted[bucket * CAP + s]);

        int r00, r01, r10, r11, x0, x1;
        float wx0, wx1, wy0, wy1, wz0, wz1;
        setup_c(p.x, p.y, p.z, r00, r01, r10, r11, x0, x1,
                wx0, wx1, wy0, wy1, wz0, wz1);
        float o = trilerp(vol, r00, r01, r10, r11, x0, x1,
                          wx0, wx1, wy0, wy1, wz0, wz1);

        __builtin_nontemporal_store(o, &out[__float_as_uint(p.w)]);
    }
}

// ---- fallback: direct kernel (any shape / small workspace) ----

__global__ __launch_bounds__(256) void VolumeExplicit_29257317220866_kernel(
    const float* __restrict__ x,
    const float* __restrict__ vol,
    float* __restrict__ out,
    int n)
{
    int tid = blockIdx.x * blockDim.x + threadIdx.x;
    int half = n >> 1;
    if (tid >= half) return;
    int iA = tid;
    int iB = tid + half;

    int a_r00, a_r01, a_r10, a_r11, a_x0, a_x1;
    float a_wx0, a_wx1, a_wy0, a_wy1, a_wz0, a_wz1;
    point_setup(x, iA, a_r00, a_r01, a_r10, a_r11, a_x0, a_x1,
                a_wx0, a_wx1, a_wy0, a_wy1, a_wz0, a_wz1);

    int b_r00, b_r01, b_r10, b_r11, b_x0, b_x1;
    float b_wx0, b_wx1, b_wy0, b_wy1, b_wz0, b_wz1;
    point_setup(x, iB, b_r00, b_r01, b_r10, b_r11, b_x0, b_x1,
                b_wx0, b_wx1, b_wy0, b_wy1, b_wz0, b_wz1);

    float oA = trilerp(vol, a_r00, a_r01, a_r10, a_r11, a_x0, a_x1,
                       a_wx0, a_wx1, a_wy0, a_wy1, a_wz0, a_wz1);
    float oB = trilerp(vol, b_r00, b_r01, b_r10, b_r11, b_x0, b_x1,
                       b_wx0, b_wx1, b_wy0, b_wy1, b_wz0, b_wz1);

    __builtin_nontemporal_store(oA, &out[iA]);
    __builtin_nontemporal_store(oB, &out[iB]);
}

extern "C" void kernel_launch(void* const* d_in, const int* in_sizes, int n_in,
                              void* d_out, int out_size, void* d_ws, size_t ws_size,
                              hipStream_t stream) {
    const float* x   = (const float*)d_in[0];   // [8, 65536, 3] fp32
    const float* vol = (const float*)d_in[1];   // [256,256,256] fp32
    float* out = (float*)d_out;                 // [8, 65536] fp32

    int n = out_size;                            // 524288 points
    size_t need = 4096 + (size_t)NB * CAP * sizeof(vfloat4);  // ~10.5 MB

    if (n == 524288 && d_ws != nullptr && ws_size >= need) {
        unsigned* cursor = (unsigned*)d_ws;
        vfloat4* sorted  = (vfloat4*)((char*)d_ws + 4096);

        hipMemsetAsync(cursor, 0, NB * sizeof(unsigned), stream);
        VolumeExplicit_scatter_kernel<<<n / 1024, 256, 0, stream>>>(
            x, vol, out, sorted, cursor);
        VolumeExplicit_gather_kernel<<<8 * 16 * WINDOWS, 256, 0, stream>>>(
            sorted, cursor, vol, out);
    } else {
        int half = n >> 1;
        int block = 256;
        int grid = (half + block - 1) / block;
        VolumeExplicit_29257317220866_kernel<<<grid, block, 0, stream>>>(x, vol, out, n);
    }
}

// Round 3
// 120.069 us; speedup vs baseline: 1.1496x; 1.1090x over previous
//
#include <hip/hip_runtime.h>

// Trilinear grid_sample (align_corners=False, zeros padding) of 256^3 fp32
// volume, scaled by 100.
//
// Round 5: halve scattered-request count via float2 x-pair loads.
//   Evidence: kernel time pinned at ~42 us across FETCH 55->129 MB and
//   occupancy 18->31% (rounds 2-4). Neither BW-bound nor wave-starved ->
//   per-lane scattered-request throughput wall (4.2M lane requests, ~6.1
//   cyc/request/CU in the L1/TA address pipe). Fix: the (x0,x1) corner pair
//   is adjacent -> one 4B-aligned dwordx2 load instead of two dwords:
//   8 -> 4 requests/point. Edge clamping folds into one bool: with
//   xb=clamp(x0,0,254), (f.x,f.y) map to (x0,x1) iff x0==xb, else swapped;
//   pre-swap the weights (wxa,wxb) once per point.
//   Sort/scatter from rounds 3-4 dropped: under the request wall, L2
//   locality is irrelevant and the scatter pass was pure overhead.

#define RES 256

// 2-wide float vector with alignment lowered to 4 so the compiler may emit a
// single global_load_dwordx2 at any dword-aligned address (gfx950 supports
// unaligned global access).
typedef float f2a4 __attribute__((ext_vector_type(2), aligned(4)));

__device__ __forceinline__ void point_setup(
    const float* __restrict__ x, int i,
    int& r00, int& r01, int& r10, int& r11, int& xb,
    float& wxa, float& wxb, float& wy0, float& wy1, float& wz0, float& wz1)
{
    float gx = __builtin_nontemporal_load(&x[3 * i + 0]) * 2.0f;
    float gy = __builtin_nontemporal_load(&x[3 * i + 1]) * 2.0f;
    float gz = __builtin_nontemporal_load(&x[3 * i + 2]) * 2.0f;

    float ix = ((gx + 1.0f) * (float)RES - 1.0f) * 0.5f;
    float iy = ((gy + 1.0f) * (float)RES - 1.0f) * 0.5f;
    float iz = ((gz + 1.0f) * (float)RES - 1.0f) * 0.5f;

    float x0f = floorf(ix), y0f = floorf(iy), z0f = floorf(iz);
    float tx = ix - x0f, ty = iy - y0f, tz = iz - z0f;

    int x0 = (int)x0f, y0 = (int)y0f, z0 = (int)z0f;
    int x1 = x0 + 1, y1 = y0 + 1, z1 = z0 + 1;

    float wx0 = (x0 >= 0 && x0 < RES) ? (1.0f - tx) : 0.0f;
    float wx1 = (x1 >= 0 && x1 < RES) ? tx : 0.0f;
    wy0 = (y0 >= 0 && y0 < RES) ? (1.0f - ty) : 0.0f;
    wy1 = (y1 >= 0 && y1 < RES) ? ty : 0.0f;
    wz0 = (z0 >= 0 && z0 < RES) ? (1.0f - tz) : 0.0f;
    wz1 = (z1 >= 0 && z1 < RES) ? tz : 0.0f;

    // float2 base column and weight mapping:
    //   xb = clamp(x0, 0, 254); load f = vol[row + xb .. xb+1].
    //   x0==xb  (interior, incl. x0=-1? no): f.x<->x0, f.y<->x1
    //   x0!=xb  (x0=-1: xb=0 -> f.x is col 0 = x1's clamped col;
    //            x0=255: xb=254 -> f.y is col 255 = x0's col;
    //            fully-out cases have wx0=wx1=0, don't-care):
    //            mapping swaps.
    xb = min(max(x0, 0), RES - 2);
    bool e0 = (x0 == xb);
    wxa = e0 ? wx0 : wx1;   // weight applied to f.x
    wxb = e0 ? wx1 : wx0;   // weight applied to f.y

    int yc0 = min(max(y0, 0), RES - 1), yc1 = min(max(y1, 0), RES - 1);
    int zc0 = min(max(z0, 0), RES - 1), zc1 = min(max(z1, 0), RES - 1);

    r00 = (zc0 * RES + yc0) * RES;
    r01 = (zc0 * RES + yc1) * RES;
    r10 = (zc1 * RES + yc0) * RES;
    r11 = (zc1 * RES + yc1) * RES;
}

__device__ __forceinline__ float trilerp(
    const float* __restrict__ vol,
    int r00, int r01, int r10, int r11, int xb,
    float wxa, float wxb, float wy0, float wy1, float wz0, float wz1)
{
    f2a4 f00 = *reinterpret_cast<const f2a4*>(vol + r00 + xb);
    f2a4 f01 = *reinterpret_cast<const f2a4*>(vol + r01 + xb);
    f2a4 f10 = *reinterpret_cast<const f2a4*>(vol + r10 + xb);
    f2a4 f11 = *reinterpret_cast<const f2a4*>(vol + r11 + xb);

    float c00 = f00.x * wxa + f00.y * wxb;
    float c01 = f01.x * wxa + f01.y * wxb;
    float c10 = f10.x * wxa + f10.y * wxb;
    float c11 = f11.x * wxa + f11.y * wxb;
    float c0 = c00 * wy0 + c01 * wy1;
    float c1 = c10 * wy0 + c11 * wy1;
    return 100.0f * (c0 * wz0 + c1 * wz1);
}

__global__ __launch_bounds__(256) void VolumeExplicit_29257317220866_kernel(
    const float* __restrict__ x,
    const float* __restrict__ vol,
    float* __restrict__ out,
    int n)
{
    int tid = blockIdx.x * blockDim.x + threadIdx.x;
    int half = n >> 1;
    if (tid >= half) return;
    int iA = tid;
    int iB = tid + half;

    // setup both points first, then issue all 8 dwordx2 volume loads
    // back-to-back so they are in flight together.
    int a_r00, a_r01, a_r10, a_r11, a_xb;
    float a_wxa, a_wxb, a_wy0, a_wy1, a_wz0, a_wz1;
    point_setup(x, iA, a_r00, a_r01, a_r10, a_r11, a_xb,
                a_wxa, a_wxb, a_wy0, a_wy1, a_wz0, a_wz1);

    int b_r00, b_r01, b_r10, b_r11, b_xb;
    float b_wxa, b_wxb, b_wy0, b_wy1, b_wz0, b_wz1;
    point_setup(x, iB, b_r00, b_r01, b_r10, b_r11, b_xb,
                b_wxa, b_wxb, b_wy0, b_wy1, b_wz0, b_wz1);

    float oA = trilerp(vol, a_r00, a_r01, a_r10, a_r11, a_xb,
                       a_wxa, a_wxb, a_wy0, a_wy1, a_wz0, a_wz1);
    float oB = trilerp(vol, b_r00, b_r01, b_r10, b_r11, b_xb,
                       b_wxa, b_wxb, b_wy0, b_wy1, b_wz0, b_wz1);

    __builtin_nontemporal_store(oA, &out[iA]);
    __builtin_nontemporal_store(oB, &out[iB]);
}

extern "C" void kernel_launch(void* const* d_in, const int* in_sizes, int n_in,
                              void* d_out, int out_size, void* d_ws, size_t ws_size,
                              hipStream_t stream) {
    const float* x   = (const float*)d_in[0];   // [8, 65536, 3] fp32
    const float* vol = (const float*)d_in[1];   // [256,256,256] fp32
    float* out = (float*)d_out;                 // [8, 65536] fp32

    int n = out_size;          // 524288 points
    int half = n >> 1;         // 2 points per thread
    int block = 256;
    int grid = (half + block - 1) / block;   // 1024 blocks
    VolumeExplicit_29257317220866_kernel<<<grid, block, 0, stream>>>(x, vol, out, n);
}